// Round 24
// baseline (195.339 us; speedup 1.0000x reference)
//
#include <hip/hip_runtime.h>
#include <hip/hip_bf16.h>

#define D64 64
#define LPAD 68  // padded bf16 LDS row (136 B): 2-way bank aliasing only (free)

typedef __attribute__((ext_vector_type(8))) short short8;
typedef __attribute__((ext_vector_type(4))) float f32x4;

__device__ inline float lane_bcast(float v, int l) {
    return __uint_as_float(__builtin_amdgcn_readlane(__float_as_uint(v), l));
}
__device__ inline float bf16_lo(unsigned u) { return __uint_as_float(u << 16); }
__device__ inline float bf16_hi(unsigned u) { return __uint_as_float(u & 0xFFFF0000u); }
__device__ inline float bf16u(unsigned short u) { return __uint_as_float((unsigned)u << 16); }
__device__ inline unsigned short f2bf(float f) {
    __hip_bfloat16 b = __float2bfloat16(f);
    return *(unsigned short*)&b;
}

// bf16 tables + Ws/Wh conversion + counts zeroing.
__global__ void prep_kernel(const float* __restrict__ emb, const int* __restrict__ mapping,
                            const int* __restrict__ q_rel,
                            const float* __restrict__ Wr, const float* __restrict__ Wqr,
                            const float* __restrict__ Wqr_b, const float* __restrict__ Ws,
                            const float* __restrict__ Wh,
                            unsigned short* __restrict__ hrmapb,
                            unsigned short* __restrict__ hrWb,
                            unsigned short* __restrict__ qrb,
                            unsigned short* __restrict__ WsB,
                            unsigned short* __restrict__ WhB,
                            int* __restrict__ counts, int nrel, int nq, int NN) {
    int b = blockIdx.x;
    int lane = threadIdx.x;
    if (b < nrel) {
        int m = mapping[b];
        float v = emb[m * D64 + lane];
        hrmapb[b * D64 + lane] = f2bf(v);
        float acc = 0.f;
#pragma unroll
        for (int d = 0; d < D64; ++d)
            acc = fmaf(lane_bcast(v, d), Wr[lane * D64 + d], acc);
        hrWb[b * D64 + lane] = f2bf(acc);
    } else if (b < nrel + nq) {
        int q = b - nrel;
        int m = mapping[q_rel[q]];
        float v = emb[m * D64 + lane];
        float acc = Wqr_b[lane];
#pragma unroll
        for (int d = 0; d < D64; ++d)
            acc = fmaf(lane_bcast(v, d), Wqr[lane * D64 + d], acc);
        qrb[q * D64 + lane] = f2bf(acc);
    } else if (b < nrel + nq + 64) {
        int c = b - nrel - nq;
        WsB[c * D64 + lane] = f2bf(Ws[c * D64 + lane]);
    } else if (b < nrel + nq + 128) {
        int c = b - nrel - nq - 64;
        WhB[c * D64 + lane] = f2bf(Wh[c * D64 + lane]);
    } else {
        int c = b - nrel - nq - 128;
        int idx = c * 64 + lane;
        if (idx < NN) counts[idx] = 0;
    }
}

// combb[(r<<5)|q] = bf16(hrW[r] + qr_attn[q])  — trivial streaming add, 1.9 MB.
__global__ void comb_kernel(const unsigned short* __restrict__ hrWb,
                            const unsigned short* __restrict__ qrb,
                            unsigned short* __restrict__ combb, int nrel) {
    int i = blockIdx.x * blockDim.x + threadIdx.x;
    int total = nrel * 32 * D64;
    if (i < total) {
        int lane = i & 63;
        int row = i >> 6;
        int r = row >> 5;
        int q = row & 31;
        combb[i] = f2bf(bf16u(hrWb[r * D64 + lane]) + bf16u(qrb[q * D64 + lane]));
    }
}

// MFMA rowmm, one wave per block; batched v[16] loads. Writes the PACKED
// pair table pairb[r][d] = hsW_bf16 | hidden_bf16<<16 (one uint store per
// lane per row; one 4B gather later fetches both values).
// Barrier-free hist tail (counts only) overlaps.
__global__ void __launch_bounds__(64)
rowmm_mfma_kernel(const float* __restrict__ in,
                  const unsigned short* __restrict__ WsB,
                  unsigned* __restrict__ pairb, int nrows,
                  const int* __restrict__ edges,
                  int* __restrict__ counts, int E) {
    __shared__ unsigned short la[16 * LPAD];
    int lane = threadIdx.x;
    int rbase = blockIdx.x * 16;

    if (rbase < nrows) {
        short8 bfrag[8];
#pragma unroll
        for (int t = 0; t < 4; ++t)
#pragma unroll
            for (int kk = 0; kk < 2; ++kk)
                bfrag[t * 2 + kk] = *(const short8*)(WsB + (size_t)(t * 16 + (lane & 15)) * D64 +
                                                     kk * 32 + (lane >> 4) * 8);

        bool full = (rbase + 16 <= nrows);
        float v[16];
        if (full) {
#pragma unroll
            for (int rr = 0; rr < 16; ++rr)
                v[rr] = in[(size_t)(rbase + rr) * D64 + lane];
        } else {
#pragma unroll
            for (int rr = 0; rr < 16; ++rr)
                v[rr] = (rbase + rr < nrows) ? in[(size_t)(rbase + rr) * D64 + lane] : 0.f;
        }
#pragma unroll
        for (int rr = 0; rr < 16; ++rr)
            la[rr * LPAD + lane] = f2bf(v[rr]);

        f32x4 acc[4];
#pragma unroll
        for (int t = 0; t < 4; ++t) acc[t] = (f32x4){0.f, 0.f, 0.f, 0.f};
#pragma unroll
        for (int kk = 0; kk < 2; ++kk) {
            short8 afrag = *(const short8*)(la + (lane & 15) * LPAD + kk * 32 + (lane >> 4) * 8);
#pragma unroll
            for (int t = 0; t < 4; ++t)
                acc[t] = __builtin_amdgcn_mfma_f32_16x16x32_bf16(afrag, bfrag[t * 2 + kk],
                                                                 acc[t], 0, 0, 0);
        }
        // pack hsW (low) | hidden (high): hidden re-read from LDS at (row,col)
#pragma unroll
        for (int t = 0; t < 4; ++t)
#pragma unroll
            for (int reg = 0; reg < 4; ++reg) {
                int rl = (lane >> 4) * 4 + reg;
                int col = t * 16 + (lane & 15);
                int row = rbase + rl;
                if (row < nrows) {
                    unsigned hid = la[rl * LPAD + col];
                    unsigned pr = (unsigned)f2bf(acc[t][reg]) | (hid << 16);
                    pairb[(size_t)row * D64 + col] = pr;
                }
            }
    }

    // hist tail: grid-stride over edge quads (counts only).
    int n4 = E >> 2;
    const uint4* e4 = (const uint4*)edges;
    for (int i4 = blockIdx.x * 64 + lane; i4 < n4; i4 += gridDim.x * 64) {
        uint4 a = e4[i4 * 3 + 0];
        uint4 b = e4[i4 * 3 + 1];
        uint4 c = e4[i4 * 3 + 2];
        atomicAdd(&counts[a.z], 1);
        atomicAdd(&counts[b.y], 1);
        atomicAdd(&counts[c.x], 1);
        atomicAdd(&counts[c.w], 1);
    }
    int tail = n4 * 4;
    int gt = blockIdx.x * 64 + lane;
    int ti = tail + gt;
    if (gt < (E - tail) && ti < E)
        atomicAdd(&counts[edges[ti * 3 + 2]], 1);
}

// Block-level exclusive scan: 1024 elements/block (256 thr x 4).
__global__ void scan1_kernel(const int* __restrict__ counts, int* __restrict__ offs,
                             int* __restrict__ partials, int n) {
    __shared__ int tsum[256];
    int t = threadIdx.x;
    int base = blockIdx.x * 1024 + t * 4;
    int v[4];
    int s = 0;
#pragma unroll
    for (int i = 0; i < 4; ++i) {
        int idx = base + i;
        int c = (idx < n) ? counts[idx] : 0;
        v[i] = s;
        s += c;
    }
    tsum[t] = s;
    __syncthreads();
    for (int off = 1; off < 256; off <<= 1) {
        int y = (t >= off) ? tsum[t - off] : 0;
        __syncthreads();
        tsum[t] += y;
        __syncthreads();
    }
    int incl = tsum[t];
    int thread_prefix = incl - s;
    if (t == 255) partials[blockIdx.x] = incl;
#pragma unroll
    for (int i = 0; i < 4; ++i) {
        int idx = base + i;
        if (idx < n) offs[idx] = thread_prefix + v[i];
    }
}

__global__ void scan2_kernel(int* partials, int nb) {
    int t = threadIdx.x;
    int own = (t < nb) ? partials[t] : 0;
    int v = own;
    for (int off = 1; off < 64; off <<= 1) {
        int y = __shfl_up(v, off, 64);
        if (t >= off) v += y;
    }
    if (t < nb) partials[t] = v - own;
}

__global__ void scan3_kernel(int* __restrict__ offs, const int* __restrict__ partials, int n) {
    int base = blockIdx.x * 1024 + threadIdx.x;
    int add = partials[blockIdx.x];
#pragma unroll
    for (int i = 0; i < 4; ++i) {
        int idx = base + i * 256;
        if (idx < n) offs[idx] += add;
    }
}

// Build CSR: rec[slot] = sub | comb<<17 (4 B records). uint4 edge reads.
// Mutates offs so afterwards offs[n] == inclusive segment end of node n.
__global__ void scatter_kernel(const int* __restrict__ edges, const int* __restrict__ r_idx,
                               int* __restrict__ offs, unsigned* __restrict__ rec, int E) {
    int i4 = blockIdx.x * blockDim.x + threadIdx.x;
    int n4 = E >> 2;
    if (i4 < n4) {
        const uint4* e4 = (const uint4*)edges;
        uint4 a = e4[i4 * 3 + 0];
        uint4 b = e4[i4 * 3 + 1];
        uint4 c = e4[i4 * 3 + 2];
        uint4 r = ((const uint4*)r_idx)[i4];
        int s0 = atomicAdd(&offs[a.z], 1);
        rec[s0] = a.x | ((((a.y << 5) | r.x)) << 17);
        int s1 = atomicAdd(&offs[b.y], 1);
        rec[s1] = a.w | ((((b.x << 5) | r.y)) << 17);
        int s2 = atomicAdd(&offs[c.x], 1);
        rec[s2] = b.z | ((((b.w << 5) | r.z)) << 17);
        int s3 = atomicAdd(&offs[c.w], 1);
        rec[s3] = c.y | ((((c.z << 5) | r.w)) << 17);
    }
    int tail = n4 * 4;
    int ti = tail + i4;
    if (i4 < (E - tail) && ti < E) {
        unsigned sub = edges[ti * 3 + 0];
        unsigned rel = edges[ti * 3 + 1];
        unsigned obj = edges[ti * 3 + 2];
        unsigned ri  = r_idx[ti];
        int s = atomicAdd(&offs[(int)obj], 1);
        rec[s] = sub | (((rel << 5) | ri) << 17);
    }
}

// FUSED alpha+aggregate: one wave per node over CSR. Per edge: one packed
// pairb gather (hsW|hidden in 4 B/lane), combb (L2-hot), hrmapb (L1-hot);
// alpha via 6-level butterfly (2-edge interleaved) + sigmoid; msg fma.
__global__ void agg_kernel(const unsigned* __restrict__ rec, const int* __restrict__ endoff,
                           const unsigned* __restrict__ pairb,
                           const unsigned short* __restrict__ combb,
                           const unsigned short* __restrict__ hrmapb,
                           const float* __restrict__ walpha_w,
                           const float* __restrict__ walpha_b,
                           unsigned short* __restrict__ aggb, int NN) {
    int tid = threadIdx.x;
    int lane = tid & 63;
    int n = (blockIdx.x * blockDim.x + tid) >> 6;
    if (n >= NN) return;
    float wa = walpha_w[lane];
    float wb = walpha_b[0];
    int start = (n == 0) ? 0 : endoff[n - 1];
    int end = endoff[n];
    start = __builtin_amdgcn_readfirstlane(start);
    end = __builtin_amdgcn_readfirstlane(end);
    float acc0 = 0.f, acc1 = 0.f;
    for (int base = start; base < end; base += 64) {
        int cnt = end - base;
        if (cnt > 64) cnt = 64;
        unsigned rv = 0;
        if (lane < cnt) rv = rec[base + lane];
        int j = 0;
        for (; j + 1 < cnt; j += 2) {
            unsigned r0 = (unsigned)__builtin_amdgcn_readlane((int)rv, j);
            unsigned r1 = (unsigned)__builtin_amdgcn_readlane((int)rv, j + 1);
            unsigned sub0 = r0 & 0x1FFFF, cb0 = r0 >> 17;
            unsigned sub1 = r1 & 0x1FFFF, cb1 = r1 >> 17;
            unsigned pv0 = pairb[(size_t)sub0 * D64 + lane];
            unsigned cv0 = (unsigned)combb[(size_t)cb0 * D64 + lane];
            unsigned mv0 = (unsigned)hrmapb[(size_t)(cb0 >> 5) * D64 + lane];
            unsigned pv1 = pairb[(size_t)sub1 * D64 + lane];
            unsigned cv1 = (unsigned)combb[(size_t)cb1 * D64 + lane];
            unsigned mv1 = (unsigned)hrmapb[(size_t)(cb1 >> 5) * D64 + lane];
            float x0 = fmaxf(bf16_lo(pv0) + __uint_as_float(cv0 << 16), 0.f) * wa;
            float x1 = fmaxf(bf16_lo(pv1) + __uint_as_float(cv1 << 16), 0.f) * wa;
            x0 += __shfl_xor(x0, 32, 64);
            x1 += __shfl_xor(x1, 32, 64);
            x0 += __shfl_xor(x0, 16, 64);
            x1 += __shfl_xor(x1, 16, 64);
            x0 += __shfl_xor(x0, 8, 64);
            x1 += __shfl_xor(x1, 8, 64);
            x0 += __shfl_xor(x0, 4, 64);
            x1 += __shfl_xor(x1, 4, 64);
            x0 += __shfl_xor(x0, 2, 64);
            x1 += __shfl_xor(x1, 2, 64);
            x0 += __shfl_xor(x0, 1, 64);
            x1 += __shfl_xor(x1, 1, 64);
            float al0 = 1.f / (1.f + __expf(-(x0 + wb)));
            float al1 = 1.f / (1.f + __expf(-(x1 + wb)));
            acc0 = fmaf(al0 * bf16_hi(pv0), __uint_as_float(mv0 << 16), acc0);
            acc1 = fmaf(al1 * bf16_hi(pv1), __uint_as_float(mv1 << 16), acc1);
        }
        if (j < cnt) {
            unsigned r0 = (unsigned)__builtin_amdgcn_readlane((int)rv, j);
            unsigned sub0 = r0 & 0x1FFFF, cb0 = r0 >> 17;
            unsigned pv0 = pairb[(size_t)sub0 * D64 + lane];
            unsigned cv0 = (unsigned)combb[(size_t)cb0 * D64 + lane];
            unsigned mv0 = (unsigned)hrmapb[(size_t)(cb0 >> 5) * D64 + lane];
            float x0 = fmaxf(bf16_lo(pv0) + __uint_as_float(cv0 << 16), 0.f) * wa;
            x0 += __shfl_xor(x0, 32, 64);
            x0 += __shfl_xor(x0, 16, 64);
            x0 += __shfl_xor(x0, 8, 64);
            x0 += __shfl_xor(x0, 4, 64);
            x0 += __shfl_xor(x0, 2, 64);
            x0 += __shfl_xor(x0, 1, 64);
            float al0 = 1.f / (1.f + __expf(-(x0 + wb)));
            acc0 = fmaf(al0 * bf16_hi(pv0), __uint_as_float(mv0 << 16), acc0);
        }
    }
    aggb[(size_t)n * D64 + lane] = f2bf(acc0 + acc1);
}

// out = relu(aggb @ Wh.T) via MFMA; A-fragments direct from global.
__global__ void rowmm_wh_kernel(const unsigned short* __restrict__ aggb,
                                const unsigned short* __restrict__ WhB,
                                float* __restrict__ out, int nrows) {
    int lane = threadIdx.x;
    int rbase = blockIdx.x * 16;
    if (rbase >= nrows) return;

    short8 bfrag[8];
#pragma unroll
    for (int t = 0; t < 4; ++t)
#pragma unroll
        for (int kk = 0; kk < 2; ++kk)
            bfrag[t * 2 + kk] = *(const short8*)(WhB + (size_t)(t * 16 + (lane & 15)) * D64 +
                                                 kk * 32 + (lane >> 4) * 8);

    f32x4 acc[4];
#pragma unroll
    for (int t = 0; t < 4; ++t) acc[t] = (f32x4){0.f, 0.f, 0.f, 0.f};
#pragma unroll
    for (int kk = 0; kk < 2; ++kk) {
        short8 afrag = *(const short8*)(aggb + (size_t)(rbase + (lane & 15)) * D64 +
                                        kk * 32 + (lane >> 4) * 8);
#pragma unroll
        for (int t = 0; t < 4; ++t)
            acc[t] = __builtin_amdgcn_mfma_f32_16x16x32_bf16(afrag, bfrag[t * 2 + kk],
                                                             acc[t], 0, 0, 0);
    }
#pragma unroll
    for (int t = 0; t < 4; ++t)
#pragma unroll
        for (int reg = 0; reg < 4; ++reg) {
            int row = rbase + (lane >> 4) * 4 + reg;
            int col = t * 16 + (lane & 15);
            if (row < nrows)
                out[(size_t)row * D64 + col] = fmaxf(acc[t][reg], 0.f);
        }
}

extern "C" void kernel_launch(void* const* d_in, const int* in_sizes, int n_in,
                              void* d_out, int out_size, void* d_ws, size_t ws_size,
                              hipStream_t stream) {
    const float* hidden   = (const float*)d_in[0];
    const int*   edges    = (const int*)d_in[1];
    const float* emb_rel  = (const float*)d_in[2];
    const int*   mapping  = (const int*)d_in[3];
    const int*   q_rel    = (const int*)d_in[4];
    const int*   r_idx    = (const int*)d_in[5];
    const float* Ws_w     = (const float*)d_in[7];
    const float* Wr_w     = (const float*)d_in[8];
    const float* Wqr_w    = (const float*)d_in[9];
    const float* Wqr_b    = (const float*)d_in[10];
    const float* walpha_w = (const float*)d_in[11];
    const float* walpha_b = (const float*)d_in[12];
    const float* Wh_w     = (const float*)d_in[13];
    float* out = (float*)d_out;

    int NN   = in_sizes[0] / D64;   // 50000
    int E    = in_sizes[5];         // 800000
    int NREL = in_sizes[3];         // 475
    int NQ   = in_sizes[4];         // 32

    // workspace layout (~29 MB)
    char* ws = (char*)d_ws;
    size_t off = 0;
    unsigned* pairb  = (unsigned*)(ws + off);       off += (size_t)NN * D64 * 4;   // 12.8 MB
    unsigned short* aggb = (unsigned short*)(ws + off); off += (size_t)NN * D64 * 2; // 6.4 MB
    unsigned* rec    = (unsigned*)(ws + off);       off += (size_t)E * 4;          // 3.2 MB
    int* counts = (int*)(ws + off);        off += (size_t)NN * sizeof(int);
    int* offs   = (int*)(ws + off);        off += (size_t)NN * sizeof(int);
    int* partials = (int*)(ws + off);      off += 64 * sizeof(int);
    unsigned short* hrmapb = (unsigned short*)(ws + off); off += (size_t)NREL * D64 * 2;
    unsigned short* hrWb   = (unsigned short*)(ws + off); off += (size_t)NREL * D64 * 2;
    unsigned short* qrb    = (unsigned short*)(ws + off); off += (size_t)NQ * D64 * 2;
    unsigned short* WsB    = (unsigned short*)(ws + off); off += (size_t)D64 * D64 * 2;
    unsigned short* WhB    = (unsigned short*)(ws + off); off += (size_t)D64 * D64 * 2;
    unsigned short* combb  = (unsigned short*)(ws + off); off += (size_t)NREL * 32 * D64 * 2; // 1.9 MB

    int NB = (NN + 1023) / 1024;  // scan blocks (49)
    int zblocks = (NN + 63) / 64;

    prep_kernel<<<NREL + NQ + 128 + zblocks, 64, 0, stream>>>(
        emb_rel, mapping, q_rel, Wr_w, Wqr_w, Wqr_b, Ws_w, Wh_w,
        hrmapb, hrWb, qrb, WsB, WhB, counts, NREL, NQ, NN);
    comb_kernel<<<(NREL * 32 * D64 + 255) / 256, 256, 0, stream>>>(hrWb, qrb, combb, NREL);
    rowmm_mfma_kernel<<<(NN + 15) / 16, 64, 0, stream>>>(hidden, WsB, pairb, NN,
                                                         edges, counts, E);
    scan1_kernel<<<NB, 256, 0, stream>>>(counts, offs, partials, NN);
    scan2_kernel<<<1, 64, 0, stream>>>(partials, NB);
    scan3_kernel<<<NB, 256, 0, stream>>>(offs, partials, NN);
    {
        int n4 = (E + 3) / 4;
        scatter_kernel<<<(n4 + 255) / 256, 256, 0, stream>>>(edges, r_idx, offs, rec, E);
    }
    agg_kernel<<<(NN * 64 + 1023) / 1024, 1024, 0, stream>>>(rec, offs, pairb, combb, hrmapb,
                                                             walpha_w, walpha_b, aggb, NN);
    rowmm_wh_kernel<<<(NN + 15) / 16, 64, 0, stream>>>(aggb, WhB, out, NN);
}

// Round 25
// 139.429 us; speedup vs baseline: 1.4010x; 1.4010x over previous
//
#include <hip/hip_runtime.h>
#include <hip/hip_bf16.h>

#define D64 64
#define LPAD 68  // padded bf16 LDS row (136 B): 2-way bank aliasing only (free)

typedef __attribute__((ext_vector_type(8))) short short8;
typedef __attribute__((ext_vector_type(4))) float f32x4;

__device__ inline float lane_bcast(float v, int l) {
    return __uint_as_float(__builtin_amdgcn_readlane(__float_as_uint(v), l));
}
__device__ inline float bf16_lo(unsigned u) { return __uint_as_float(u << 16); }
__device__ inline float bf16_hi(unsigned u) { return __uint_as_float(u & 0xFFFF0000u); }
__device__ inline float bf16u(unsigned short u) { return __uint_as_float((unsigned)u << 16); }
__device__ inline unsigned short f2bf(float f) {
    __hip_bfloat16 b = __float2bfloat16(f);
    return *(unsigned short*)&b;
}

// bf16 tables + Ws/Wh conversion + counts zeroing. hrW computed ONCE per
// relation (475 rows); comb is a separate trivial add pass.
__global__ void prep_kernel(const float* __restrict__ emb, const int* __restrict__ mapping,
                            const int* __restrict__ q_rel,
                            const float* __restrict__ Wr, const float* __restrict__ Wqr,
                            const float* __restrict__ Wqr_b, const float* __restrict__ Ws,
                            const float* __restrict__ Wh,
                            unsigned short* __restrict__ hrmapb,
                            unsigned short* __restrict__ hrWb,
                            unsigned short* __restrict__ qrb,
                            unsigned short* __restrict__ WsB,
                            unsigned short* __restrict__ WhB,
                            int* __restrict__ counts, int nrel, int nq, int NN) {
    int b = blockIdx.x;
    int lane = threadIdx.x;
    if (b < nrel) {
        int m = mapping[b];
        float v = emb[m * D64 + lane];
        hrmapb[b * D64 + lane] = f2bf(v);
        float acc = 0.f;
#pragma unroll
        for (int d = 0; d < D64; ++d)
            acc = fmaf(lane_bcast(v, d), Wr[lane * D64 + d], acc);
        hrWb[b * D64 + lane] = f2bf(acc);
    } else if (b < nrel + nq) {
        int q = b - nrel;
        int m = mapping[q_rel[q]];
        float v = emb[m * D64 + lane];
        float acc = Wqr_b[lane];
#pragma unroll
        for (int d = 0; d < D64; ++d)
            acc = fmaf(lane_bcast(v, d), Wqr[lane * D64 + d], acc);
        qrb[q * D64 + lane] = f2bf(acc);
    } else if (b < nrel + nq + 64) {
        int c = b - nrel - nq;
        WsB[c * D64 + lane] = f2bf(Ws[c * D64 + lane]);
    } else if (b < nrel + nq + 128) {
        int c = b - nrel - nq - 64;
        WhB[c * D64 + lane] = f2bf(Wh[c * D64 + lane]);
    } else {
        int c = b - nrel - nq - 128;
        int idx = c * 64 + lane;
        if (idx < NN) counts[idx] = 0;
    }
}

// combb[(r<<5)|q] = bf16(hrW[r] + qr_attn[q])  — trivial streaming add.
__global__ void comb_kernel(const unsigned short* __restrict__ hrWb,
                            const unsigned short* __restrict__ qrb,
                            unsigned short* __restrict__ combb, int nrel) {
    int i = blockIdx.x * blockDim.x + threadIdx.x;
    int total = nrel * 32 * D64;
    if (i < total) {
        int lane = i & 63;
        int row = i >> 6;
        int r = row >> 5;
        int q = row & 31;
        combb[i] = f2bf(bf16u(hrWb[r * D64 + lane]) + bf16u(qrb[q * D64 + lane]));
    }
}

// MFMA rowmm, one wave per block. All 16 row loads batched into registers
// before any use (16 loads in flight -> latency tolerant).
// Barrier-free hist/pack tail overlaps.
__global__ void __launch_bounds__(64)
rowmm_mfma_kernel(const float* __restrict__ in,
                  const unsigned short* __restrict__ WsB,
                  unsigned short* __restrict__ outb,
                  unsigned short* __restrict__ inb, int nrows,
                  const int* __restrict__ edges, const int* __restrict__ r_idx,
                  int* __restrict__ counts, uint2* __restrict__ epack, int E) {
    __shared__ unsigned short la[16 * LPAD];
    int lane = threadIdx.x;
    int rbase = blockIdx.x * 16;

    if (rbase < nrows) {
        short8 bfrag[8];
#pragma unroll
        for (int t = 0; t < 4; ++t)
#pragma unroll
            for (int kk = 0; kk < 2; ++kk)
                bfrag[t * 2 + kk] = *(const short8*)(WsB + (size_t)(t * 16 + (lane & 15)) * D64 +
                                                     kk * 32 + (lane >> 4) * 8);

        bool full = (rbase + 16 <= nrows);
        float v[16];
        if (full) {
#pragma unroll
            for (int rr = 0; rr < 16; ++rr)
                v[rr] = in[(size_t)(rbase + rr) * D64 + lane];
        } else {
#pragma unroll
            for (int rr = 0; rr < 16; ++rr)
                v[rr] = (rbase + rr < nrows) ? in[(size_t)(rbase + rr) * D64 + lane] : 0.f;
        }
#pragma unroll
        for (int rr = 0; rr < 16; ++rr) {
            unsigned short bb = f2bf(v[rr]);
            if (rbase + rr < nrows) inb[(size_t)(rbase + rr) * D64 + lane] = bb;
            la[rr * LPAD + lane] = bb;
        }

        f32x4 acc[4];
#pragma unroll
        for (int t = 0; t < 4; ++t) acc[t] = (f32x4){0.f, 0.f, 0.f, 0.f};
#pragma unroll
        for (int kk = 0; kk < 2; ++kk) {
            short8 afrag = *(const short8*)(la + (lane & 15) * LPAD + kk * 32 + (lane >> 4) * 8);
#pragma unroll
            for (int t = 0; t < 4; ++t)
                acc[t] = __builtin_amdgcn_mfma_f32_16x16x32_bf16(afrag, bfrag[t * 2 + kk],
                                                                 acc[t], 0, 0, 0);
        }
#pragma unroll
        for (int t = 0; t < 4; ++t)
#pragma unroll
            for (int reg = 0; reg < 4; ++reg) {
                int row = rbase + (lane >> 4) * 4 + reg;
                int col = t * 16 + (lane & 15);
                if (row < nrows)
                    outb[(size_t)row * D64 + col] = f2bf(acc[t][reg]);
            }
    }

    // hist + pack tail: grid-stride over edge quads.
    int n4 = E >> 2;
    const uint4* e4 = (const uint4*)edges;
    for (int i4 = blockIdx.x * 64 + lane; i4 < n4; i4 += gridDim.x * 64) {
        uint4 a = e4[i4 * 3 + 0];
        uint4 b = e4[i4 * 3 + 1];
        uint4 c = e4[i4 * 3 + 2];
        uint4 r = ((const uint4*)r_idx)[i4];
        uint4 p01 = make_uint4(a.x | ((((a.y << 5) | r.x)) << 17), a.z,
                               a.w | ((((b.x << 5) | r.y)) << 17), b.y);
        uint4 p23 = make_uint4(b.z | ((((b.w << 5) | r.z)) << 17), c.x,
                               c.y | ((((c.z << 5) | r.w)) << 17), c.w);
        ((uint4*)epack)[i4 * 2 + 0] = p01;
        ((uint4*)epack)[i4 * 2 + 1] = p23;
        atomicAdd(&counts[a.z], 1);
        atomicAdd(&counts[b.y], 1);
        atomicAdd(&counts[c.x], 1);
        atomicAdd(&counts[c.w], 1);
    }
    int tail = n4 * 4;
    int gt = blockIdx.x * 64 + lane;
    int ti = tail + gt;
    if (gt < (E - tail) && ti < E) {
        unsigned sub = edges[ti * 3 + 0];
        unsigned rel = edges[ti * 3 + 1];
        unsigned obj = edges[ti * 3 + 2];
        unsigned ri  = r_idx[ti];
        epack[ti] = make_uint2(sub | (((rel << 5) | ri) << 17), obj);
        atomicAdd(&counts[obj], 1);
    }
}

// Block-level exclusive scan: 1024 elements/block (256 thr x 4).
__global__ void scan1_kernel(const int* __restrict__ counts, int* __restrict__ offs,
                             int* __restrict__ partials, int n) {
    __shared__ int tsum[256];
    int t = threadIdx.x;
    int base = blockIdx.x * 1024 + t * 4;
    int v[4];
    int s = 0;
#pragma unroll
    for (int i = 0; i < 4; ++i) {
        int idx = base + i;
        int c = (idx < n) ? counts[idx] : 0;
        v[i] = s;
        s += c;
    }
    tsum[t] = s;
    __syncthreads();
    for (int off = 1; off < 256; off <<= 1) {
        int y = (t >= off) ? tsum[t - off] : 0;
        __syncthreads();
        tsum[t] += y;
        __syncthreads();
    }
    int incl = tsum[t];
    int thread_prefix = incl - s;
    if (t == 255) partials[blockIdx.x] = incl;
#pragma unroll
    for (int i = 0; i < 4; ++i) {
        int idx = base + i;
        if (idx < n) offs[idx] = thread_prefix + v[i];
    }
}

__global__ void scan2_kernel(int* partials, int nb) {
    int t = threadIdx.x;
    int own = (t < nb) ? partials[t] : 0;
    int v = own;
    for (int off = 1; off < 64; off <<= 1) {
        int y = __shfl_up(v, off, 64);
        if (t >= off) v += y;
    }
    if (t < nb) partials[t] = v - own;
}

__global__ void scan3_kernel(int* __restrict__ offs, const int* __restrict__ partials, int n) {
    int base = blockIdx.x * 1024 + threadIdx.x;
    int add = partials[blockIdx.x];
#pragma unroll
    for (int i = 0; i < 4; ++i) {
        int idx = base + i * 256;
        if (idx < n) offs[idx] += add;
    }
}

// 8 lanes per edge, TWO edges per thread (e and e+half). Per edge: 2 gathers
// (hsWb[sub] random + combb L2-hot). Leader: sigmoid + CSR slot + rec store.
__global__ void alpha_scatter_kernel(const uint2* __restrict__ epack,
                                     const unsigned short* __restrict__ hsWb,
                                     const unsigned short* __restrict__ combb,
                                     const float* __restrict__ walpha_w,
                                     const float* __restrict__ walpha_b,
                                     int* __restrict__ offs, int2* __restrict__ rec,
                                     int E, int half) {
    int tid = blockIdx.x * blockDim.x + threadIdx.x;
    int e0 = tid >> 3;
    int l = tid & 7;
    if (e0 >= half) return;
    int e1 = e0 + half;
    bool has1 = (e1 < E);

    uint2 p0 = epack[e0];
    uint2 p1 = has1 ? epack[e1] : make_uint2(0u, 0u);
    unsigned sub0 = p0.x & 0x1FFFF, comb0 = p0.x >> 17;
    unsigned sub1 = p1.x & 0x1FFFF, comb1 = p1.x >> 17;
    int obj0 = (int)p0.y, obj1 = (int)p1.y;

    uint4 hv0 = *(const uint4*)(hsWb  + (size_t)sub0  * D64 + l * 8);
    uint4 cv0 = *(const uint4*)(combb + (size_t)comb0 * D64 + l * 8);
    uint4 hv1 = *(const uint4*)(hsWb  + (size_t)sub1  * D64 + l * 8);
    uint4 cv1 = *(const uint4*)(combb + (size_t)comb1 * D64 + l * 8);
    const float4* w = (const float4*)(walpha_w + l * 8);
    float4 w0 = w[0], w1 = w[1];

    float x0, x1;
    x0 = fmaxf(bf16_lo(hv0.x) + bf16_lo(cv0.x), 0.f) * w0.x;
    x0 = fmaf(fmaxf(bf16_hi(hv0.x) + bf16_hi(cv0.x), 0.f), w0.y, x0);
    x0 = fmaf(fmaxf(bf16_lo(hv0.y) + bf16_lo(cv0.y), 0.f), w0.z, x0);
    x0 = fmaf(fmaxf(bf16_hi(hv0.y) + bf16_hi(cv0.y), 0.f), w0.w, x0);
    x0 = fmaf(fmaxf(bf16_lo(hv0.z) + bf16_lo(cv0.z), 0.f), w1.x, x0);
    x0 = fmaf(fmaxf(bf16_hi(hv0.z) + bf16_hi(cv0.z), 0.f), w1.y, x0);
    x0 = fmaf(fmaxf(bf16_lo(hv0.w) + bf16_lo(cv0.w), 0.f), w1.z, x0);
    x0 = fmaf(fmaxf(bf16_hi(hv0.w) + bf16_hi(cv0.w), 0.f), w1.w, x0);

    x1 = fmaxf(bf16_lo(hv1.x) + bf16_lo(cv1.x), 0.f) * w0.x;
    x1 = fmaf(fmaxf(bf16_hi(hv1.x) + bf16_hi(cv1.x), 0.f), w0.y, x1);
    x1 = fmaf(fmaxf(bf16_lo(hv1.y) + bf16_lo(cv1.y), 0.f), w0.z, x1);
    x1 = fmaf(fmaxf(bf16_hi(hv1.y) + bf16_hi(cv1.y), 0.f), w0.w, x1);
    x1 = fmaf(fmaxf(bf16_lo(hv1.z) + bf16_lo(cv1.z), 0.f), w1.x, x1);
    x1 = fmaf(fmaxf(bf16_hi(hv1.z) + bf16_hi(cv1.z), 0.f), w1.y, x1);
    x1 = fmaf(fmaxf(bf16_lo(hv1.w) + bf16_lo(cv1.w), 0.f), w1.z, x1);
    x1 = fmaf(fmaxf(bf16_hi(hv1.w) + bf16_hi(cv1.w), 0.f), w1.w, x1);

    x0 += __shfl_xor(x0, 4, 64);
    x1 += __shfl_xor(x1, 4, 64);
    x0 += __shfl_xor(x0, 2, 64);
    x1 += __shfl_xor(x1, 2, 64);
    x0 += __shfl_xor(x0, 1, 64);
    x1 += __shfl_xor(x1, 1, 64);

    if (l == 0) {
        float wb = walpha_b[0];
        float a0 = 1.f / (1.f + __expf(-(x0 + wb)));
        int rel0 = comb0 >> 5;
        int slot0 = atomicAdd(&offs[obj0], 1);
        rec[slot0] = make_int2((int)(sub0 | (rel0 << 17)), __float_as_int(a0));
        if (has1) {
            float a1 = 1.f / (1.f + __expf(-(x1 + wb)));
            int rel1 = comb1 >> 5;
            int slot1 = atomicAdd(&offs[obj1], 1);
            rec[slot1] = make_int2((int)(sub1 | (rel1 << 17)), __float_as_int(a1));
        }
    }
}

// One wave per node: CSR gather-FMA (8-deep unroll, 16 gathers in flight),
// writes aggb as bf16.
__global__ void agg_kernel(const int2* __restrict__ rec, const int* __restrict__ endoff,
                           const unsigned short* __restrict__ hiddenb,
                           const unsigned short* __restrict__ hrmapb,
                           unsigned short* __restrict__ aggb, int NN) {
    int tid = threadIdx.x;
    int lane = tid & 63;
    int n = (blockIdx.x * blockDim.x + tid) >> 6;
    if (n >= NN) return;
    int start = (n == 0) ? 0 : endoff[n - 1];
    int end = endoff[n];
    start = __builtin_amdgcn_readfirstlane(start);
    end = __builtin_amdgcn_readfirstlane(end);
    float acc0 = 0.f, acc1 = 0.f, acc2 = 0.f, acc3 = 0.f;
    for (int base = start; base < end; base += 64) {
        int cnt = end - base;
        if (cnt > 64) cnt = 64;
        int rx = 0, ry = 0;
        if (lane < cnt) {
            int2 r = rec[base + lane];
            rx = r.x; ry = r.y;
        }
        int j = 0;
        for (; j + 7 < cnt; j += 8) {
            int a_rx[8], a_ry[8];
#pragma unroll
            for (int k = 0; k < 8; ++k) {
                a_rx[k] = __builtin_amdgcn_readlane(rx, j + k);
                a_ry[k] = __builtin_amdgcn_readlane(ry, j + k);
            }
            float h[8], m[8];
#pragma unroll
            for (int k = 0; k < 8; ++k) {
                h[k] = bf16u(hiddenb[(size_t)(a_rx[k] & 0x1FFFF) * D64 + lane]);
                m[k] = bf16u(hrmapb[(size_t)((unsigned)a_rx[k] >> 17) * D64 + lane]);
            }
            acc0 = fmaf(__uint_as_float(a_ry[0]) * h[0], m[0], acc0);
            acc1 = fmaf(__uint_as_float(a_ry[1]) * h[1], m[1], acc1);
            acc2 = fmaf(__uint_as_float(a_ry[2]) * h[2], m[2], acc2);
            acc3 = fmaf(__uint_as_float(a_ry[3]) * h[3], m[3], acc3);
            acc0 = fmaf(__uint_as_float(a_ry[4]) * h[4], m[4], acc0);
            acc1 = fmaf(__uint_as_float(a_ry[5]) * h[5], m[5], acc1);
            acc2 = fmaf(__uint_as_float(a_ry[6]) * h[6], m[6], acc2);
            acc3 = fmaf(__uint_as_float(a_ry[7]) * h[7], m[7], acc3);
        }
        for (; j + 3 < cnt; j += 4) {
            int rx0 = __builtin_amdgcn_readlane(rx, j);
            int ry0 = __builtin_amdgcn_readlane(ry, j);
            int rx1 = __builtin_amdgcn_readlane(rx, j + 1);
            int ry1 = __builtin_amdgcn_readlane(ry, j + 1);
            int rx2 = __builtin_amdgcn_readlane(rx, j + 2);
            int ry2 = __builtin_amdgcn_readlane(ry, j + 2);
            int rx3 = __builtin_amdgcn_readlane(rx, j + 3);
            int ry3 = __builtin_amdgcn_readlane(ry, j + 3);
            float h0 = bf16u(hiddenb[(size_t)(rx0 & 0x1FFFF) * D64 + lane]);
            float m0 = bf16u(hrmapb[(size_t)((unsigned)rx0 >> 17) * D64 + lane]);
            float h1 = bf16u(hiddenb[(size_t)(rx1 & 0x1FFFF) * D64 + lane]);
            float m1 = bf16u(hrmapb[(size_t)((unsigned)rx1 >> 17) * D64 + lane]);
            float h2 = bf16u(hiddenb[(size_t)(rx2 & 0x1FFFF) * D64 + lane]);
            float m2 = bf16u(hrmapb[(size_t)((unsigned)rx2 >> 17) * D64 + lane]);
            float h3 = bf16u(hiddenb[(size_t)(rx3 & 0x1FFFF) * D64 + lane]);
            float m3 = bf16u(hrmapb[(size_t)((unsigned)rx3 >> 17) * D64 + lane]);
            acc0 = fmaf(__uint_as_float(ry0) * h0, m0, acc0);
            acc1 = fmaf(__uint_as_float(ry1) * h1, m1, acc1);
            acc2 = fmaf(__uint_as_float(ry2) * h2, m2, acc2);
            acc3 = fmaf(__uint_as_float(ry3) * h3, m3, acc3);
        }
        for (; j < cnt; ++j) {
            int rx0 = __builtin_amdgcn_readlane(rx, j);
            int ry0 = __builtin_amdgcn_readlane(ry, j);
            float h0 = bf16u(hiddenb[(size_t)(rx0 & 0x1FFFF) * D64 + lane]);
            float m0 = bf16u(hrmapb[(size_t)((unsigned)rx0 >> 17) * D64 + lane]);
            acc0 = fmaf(__uint_as_float(ry0) * h0, m0, acc0);
        }
    }
    aggb[(size_t)n * D64 + lane] = f2bf((acc0 + acc1) + (acc2 + acc3));
}

// out = relu(aggb @ Wh.T) via MFMA; A-fragments direct from global.
__global__ void rowmm_wh_kernel(const unsigned short* __restrict__ aggb,
                                const unsigned short* __restrict__ WhB,
                                float* __restrict__ out, int nrows) {
    int lane = threadIdx.x;
    int rbase = blockIdx.x * 16;
    if (rbase >= nrows) return;

    short8 bfrag[8];
#pragma unroll
    for (int t = 0; t < 4; ++t)
#pragma unroll
        for (int kk = 0; kk < 2; ++kk)
            bfrag[t * 2 + kk] = *(const short8*)(WhB + (size_t)(t * 16 + (lane & 15)) * D64 +
                                                 kk * 32 + (lane >> 4) * 8);

    f32x4 acc[4];
#pragma unroll
    for (int t = 0; t < 4; ++t) acc[t] = (f32x4){0.f, 0.f, 0.f, 0.f};
#pragma unroll
    for (int kk = 0; kk < 2; ++kk) {
        short8 afrag = *(const short8*)(aggb + (size_t)(rbase + (lane & 15)) * D64 +
                                        kk * 32 + (lane >> 4) * 8);
#pragma unroll
        for (int t = 0; t < 4; ++t)
            acc[t] = __builtin_amdgcn_mfma_f32_16x16x32_bf16(afrag, bfrag[t * 2 + kk],
                                                             acc[t], 0, 0, 0);
    }
#pragma unroll
    for (int t = 0; t < 4; ++t)
#pragma unroll
        for (int reg = 0; reg < 4; ++reg) {
            int row = rbase + (lane >> 4) * 4 + reg;
            int col = t * 16 + (lane & 15);
            if (row < nrows)
                out[(size_t)row * D64 + col] = fmaxf(acc[t][reg], 0.f);
        }
}

extern "C" void kernel_launch(void* const* d_in, const int* in_sizes, int n_in,
                              void* d_out, int out_size, void* d_ws, size_t ws_size,
                              hipStream_t stream) {
    const float* hidden   = (const float*)d_in[0];
    const int*   edges    = (const int*)d_in[1];
    const float* emb_rel  = (const float*)d_in[2];
    const int*   mapping  = (const int*)d_in[3];
    const int*   q_rel    = (const int*)d_in[4];
    const int*   r_idx    = (const int*)d_in[5];
    const float* Ws_w     = (const float*)d_in[7];
    const float* Wr_w     = (const float*)d_in[8];
    const float* Wqr_w    = (const float*)d_in[9];
    const float* Wqr_b    = (const float*)d_in[10];
    const float* walpha_w = (const float*)d_in[11];
    const float* walpha_b = (const float*)d_in[12];
    const float* Wh_w     = (const float*)d_in[13];
    float* out = (float*)d_out;

    int NN   = in_sizes[0] / D64;   // 50000
    int E    = in_sizes[5];         // 800000
    int NREL = in_sizes[3];         // 475
    int NQ   = in_sizes[4];         // 32

    // workspace layout (~28 MB); aggb aliases epack (dead after alpha_scatter)
    char* ws = (char*)d_ws;
    size_t off = 0;
    unsigned short* hsWb    = (unsigned short*)(ws + off); off += (size_t)NN * D64 * 2;  // 6.4 MB
    unsigned short* hiddenb = (unsigned short*)(ws + off); off += (size_t)NN * D64 * 2;  // 6.4 MB
    int2*  rec  = (int2*)(ws + off);       off += (size_t)E * sizeof(int2);              // 6.4 MB
    uint2* epack = (uint2*)(ws + off);     off += (size_t)E * sizeof(uint2);             // 6.4 MB
    unsigned short* aggb = (unsigned short*)epack;  // alias: epack dead before agg runs
    int* counts = (int*)(ws + off);        off += (size_t)NN * sizeof(int);              // 0.2 MB
    int* offs   = (int*)(ws + off);        off += (size_t)NN * sizeof(int);              // 0.2 MB
    int* partials = (int*)(ws + off);      off += 64 * sizeof(int);
    unsigned short* hrmapb = (unsigned short*)(ws + off); off += (size_t)NREL * D64 * 2;
    unsigned short* hrWb   = (unsigned short*)(ws + off); off += (size_t)NREL * D64 * 2;
    unsigned short* qrb    = (unsigned short*)(ws + off); off += (size_t)NQ * D64 * 2;
    unsigned short* WsB    = (unsigned short*)(ws + off); off += (size_t)D64 * D64 * 2;  // 8 KB
    unsigned short* WhB    = (unsigned short*)(ws + off); off += (size_t)D64 * D64 * 2;  // 8 KB
    unsigned short* combb  = (unsigned short*)(ws + off); off += (size_t)NREL * 32 * D64 * 2; // 1.9 MB

    int NB = (NN + 1023) / 1024;  // scan blocks (49)
    int zblocks = (NN + 63) / 64;

    prep_kernel<<<NREL + NQ + 128 + zblocks, 64, 0, stream>>>(
        emb_rel, mapping, q_rel, Wr_w, Wqr_w, Wqr_b, Ws_w, Wh_w,
        hrmapb, hrWb, qrb, WsB, WhB, counts, NREL, NQ, NN);
    comb_kernel<<<(NREL * 32 * D64 + 255) / 256, 256, 0, stream>>>(hrWb, qrb, combb, NREL);
    rowmm_mfma_kernel<<<(NN + 15) / 16, 64, 0, stream>>>(hidden, WsB, hsWb, hiddenb, NN,
                                                         edges, r_idx, counts, epack, E);
    scan1_kernel<<<NB, 256, 0, stream>>>(counts, offs, partials, NN);
    scan2_kernel<<<1, 64, 0, stream>>>(partials, NB);
    scan3_kernel<<<NB, 256, 0, stream>>>(offs, partials, NN);
    {
        int half = (E + 1) / 2;
        long long threads = (long long)half * 8;
        int blocks = (int)((threads + 255) / 256);
        alpha_scatter_kernel<<<blocks, 256, 0, stream>>>(epack, hsWb, combb,
                                                         walpha_w, walpha_b, offs, rec, E, half);
    }
    agg_kernel<<<(NN * 64 + 1023) / 1024, 1024, 0, stream>>>(rec, offs, hiddenb, hrmapb,
                                                             aggb, NN);
    rowmm_wh_kernel<<<(NN + 15) / 16, 64, 0, stream>>>(aggb, WhB, out, NN);
}

// Round 26
// 137.790 us; speedup vs baseline: 1.4177x; 1.0119x over previous
//
#include <hip/hip_runtime.h>
#include <hip/hip_bf16.h>
#include <hip/hip_fp8.h>

#define D64 64
#define LPAD 68  // padded bf16 LDS row (136 B): 2-way bank aliasing only (free)

typedef __attribute__((ext_vector_type(8))) short short8;
typedef __attribute__((ext_vector_type(4))) float f32x4;

__device__ inline float lane_bcast(float v, int l) {
    return __uint_as_float(__builtin_amdgcn_readlane(__float_as_uint(v), l));
}
__device__ inline float bf16_lo(unsigned u) { return __uint_as_float(u << 16); }
__device__ inline float bf16_hi(unsigned u) { return __uint_as_float(u & 0xFFFF0000u); }
__device__ inline float bf16u(unsigned short u) { return __uint_as_float((unsigned)u << 16); }
__device__ inline unsigned short f2bf(float f) {
    __hip_bfloat16 b = __float2bfloat16(f);
    return *(unsigned short*)&b;
}
__device__ inline unsigned char f2fp8(float f) {
    __hip_fp8_e4m3 t(f);
    return (unsigned char)t.__x;
}
__device__ inline float fp8f(unsigned b) {
    __hip_fp8_e4m3 t;
    t.__x = (__hip_fp8_storage_t)b;
    return (float)t;
}

// bf16 tables + Ws/Wh conversion + counts zeroing.
__global__ void prep_kernel(const float* __restrict__ emb, const int* __restrict__ mapping,
                            const int* __restrict__ q_rel,
                            const float* __restrict__ Wr, const float* __restrict__ Wqr,
                            const float* __restrict__ Wqr_b, const float* __restrict__ Ws,
                            const float* __restrict__ Wh,
                            unsigned short* __restrict__ hrmapb,
                            unsigned short* __restrict__ hrWb,
                            unsigned short* __restrict__ qrb,
                            unsigned short* __restrict__ WsB,
                            unsigned short* __restrict__ WhB,
                            int* __restrict__ counts, int nrel, int nq, int NN) {
    int b = blockIdx.x;
    int lane = threadIdx.x;
    if (b < nrel) {
        int m = mapping[b];
        float v = emb[m * D64 + lane];
        hrmapb[b * D64 + lane] = f2bf(v);
        float acc = 0.f;
#pragma unroll
        for (int d = 0; d < D64; ++d)
            acc = fmaf(lane_bcast(v, d), Wr[lane * D64 + d], acc);
        hrWb[b * D64 + lane] = f2bf(acc);
    } else if (b < nrel + nq) {
        int q = b - nrel;
        int m = mapping[q_rel[q]];
        float v = emb[m * D64 + lane];
        float acc = Wqr_b[lane];
#pragma unroll
        for (int d = 0; d < D64; ++d)
            acc = fmaf(lane_bcast(v, d), Wqr[lane * D64 + d], acc);
        qrb[q * D64 + lane] = f2bf(acc);
    } else if (b < nrel + nq + 64) {
        int c = b - nrel - nq;
        WsB[c * D64 + lane] = f2bf(Ws[c * D64 + lane]);
    } else if (b < nrel + nq + 128) {
        int c = b - nrel - nq - 64;
        WhB[c * D64 + lane] = f2bf(Wh[c * D64 + lane]);
    } else {
        int c = b - nrel - nq - 128;
        int idx = c * 64 + lane;
        if (idx < NN) counts[idx] = 0;
    }
}

// combb[(r<<5)|q] = bf16(hrW[r] + qr_attn[q])  — trivial streaming add.
__global__ void comb_kernel(const unsigned short* __restrict__ hrWb,
                            const unsigned short* __restrict__ qrb,
                            unsigned short* __restrict__ combb, int nrel) {
    int i = blockIdx.x * blockDim.x + threadIdx.x;
    int total = nrel * 32 * D64;
    if (i < total) {
        int lane = i & 63;
        int row = i >> 6;
        int r = row >> 5;
        int q = row & 31;
        combb[i] = f2bf(bf16u(hrWb[r * D64 + lane]) + bf16u(qrb[q * D64 + lane]));
    }
}

// MFMA rowmm, one wave per block. Batched v[16] loads. hsW output stored as
// FP8 e4m3 (3.2 MB table -> fits per-XCD L2 for alpha's random gathers;
// sigmoid damps the quantization error). hidden copy stays bf16 (inb).
// Barrier-free hist/pack tail overlaps.
__global__ void __launch_bounds__(64)
rowmm_mfma_kernel(const float* __restrict__ in,
                  const unsigned short* __restrict__ WsB,
                  unsigned char* __restrict__ out8,
                  unsigned short* __restrict__ inb, int nrows,
                  const int* __restrict__ edges, const int* __restrict__ r_idx,
                  int* __restrict__ counts, uint2* __restrict__ epack, int E) {
    __shared__ unsigned short la[16 * LPAD];
    int lane = threadIdx.x;
    int rbase = blockIdx.x * 16;

    if (rbase < nrows) {
        short8 bfrag[8];
#pragma unroll
        for (int t = 0; t < 4; ++t)
#pragma unroll
            for (int kk = 0; kk < 2; ++kk)
                bfrag[t * 2 + kk] = *(const short8*)(WsB + (size_t)(t * 16 + (lane & 15)) * D64 +
                                                     kk * 32 + (lane >> 4) * 8);

        bool full = (rbase + 16 <= nrows);
        float v[16];
        if (full) {
#pragma unroll
            for (int rr = 0; rr < 16; ++rr)
                v[rr] = in[(size_t)(rbase + rr) * D64 + lane];
        } else {
#pragma unroll
            for (int rr = 0; rr < 16; ++rr)
                v[rr] = (rbase + rr < nrows) ? in[(size_t)(rbase + rr) * D64 + lane] : 0.f;
        }
#pragma unroll
        for (int rr = 0; rr < 16; ++rr) {
            unsigned short bb = f2bf(v[rr]);
            if (rbase + rr < nrows) inb[(size_t)(rbase + rr) * D64 + lane] = bb;
            la[rr * LPAD + lane] = bb;
        }

        f32x4 acc[4];
#pragma unroll
        for (int t = 0; t < 4; ++t) acc[t] = (f32x4){0.f, 0.f, 0.f, 0.f};
#pragma unroll
        for (int kk = 0; kk < 2; ++kk) {
            short8 afrag = *(const short8*)(la + (lane & 15) * LPAD + kk * 32 + (lane >> 4) * 8);
#pragma unroll
            for (int t = 0; t < 4; ++t)
                acc[t] = __builtin_amdgcn_mfma_f32_16x16x32_bf16(afrag, bfrag[t * 2 + kk],
                                                                 acc[t], 0, 0, 0);
        }
#pragma unroll
        for (int t = 0; t < 4; ++t)
#pragma unroll
            for (int reg = 0; reg < 4; ++reg) {
                int row = rbase + (lane >> 4) * 4 + reg;
                int col = t * 16 + (lane & 15);
                if (row < nrows)
                    out8[(size_t)row * D64 + col] = f2fp8(acc[t][reg]);
            }
    }

    // hist + pack tail: grid-stride over edge quads.
    int n4 = E >> 2;
    const uint4* e4 = (const uint4*)edges;
    for (int i4 = blockIdx.x * 64 + lane; i4 < n4; i4 += gridDim.x * 64) {
        uint4 a = e4[i4 * 3 + 0];
        uint4 b = e4[i4 * 3 + 1];
        uint4 c = e4[i4 * 3 + 2];
        uint4 r = ((const uint4*)r_idx)[i4];
        uint4 p01 = make_uint4(a.x | ((((a.y << 5) | r.x)) << 17), a.z,
                               a.w | ((((b.x << 5) | r.y)) << 17), b.y);
        uint4 p23 = make_uint4(b.z | ((((b.w << 5) | r.z)) << 17), c.x,
                               c.y | ((((c.z << 5) | r.w)) << 17), c.w);
        ((uint4*)epack)[i4 * 2 + 0] = p01;
        ((uint4*)epack)[i4 * 2 + 1] = p23;
        atomicAdd(&counts[a.z], 1);
        atomicAdd(&counts[b.y], 1);
        atomicAdd(&counts[c.x], 1);
        atomicAdd(&counts[c.w], 1);
    }
    int tail = n4 * 4;
    int gt = blockIdx.x * 64 + lane;
    int ti = tail + gt;
    if (gt < (E - tail) && ti < E) {
        unsigned sub = edges[ti * 3 + 0];
        unsigned rel = edges[ti * 3 + 1];
        unsigned obj = edges[ti * 3 + 2];
        unsigned ri  = r_idx[ti];
        epack[ti] = make_uint2(sub | (((rel << 5) | ri) << 17), obj);
        atomicAdd(&counts[obj], 1);
    }
}

// Block-level exclusive scan: 1024 elements/block (256 thr x 4).
__global__ void scan1_kernel(const int* __restrict__ counts, int* __restrict__ offs,
                             int* __restrict__ partials, int n) {
    __shared__ int tsum[256];
    int t = threadIdx.x;
    int base = blockIdx.x * 1024 + t * 4;
    int v[4];
    int s = 0;
#pragma unroll
    for (int i = 0; i < 4; ++i) {
        int idx = base + i;
        int c = (idx < n) ? counts[idx] : 0;
        v[i] = s;
        s += c;
    }
    tsum[t] = s;
    __syncthreads();
    for (int off = 1; off < 256; off <<= 1) {
        int y = (t >= off) ? tsum[t - off] : 0;
        __syncthreads();
        tsum[t] += y;
        __syncthreads();
    }
    int incl = tsum[t];
    int thread_prefix = incl - s;
    if (t == 255) partials[blockIdx.x] = incl;
#pragma unroll
    for (int i = 0; i < 4; ++i) {
        int idx = base + i;
        if (idx < n) offs[idx] = thread_prefix + v[i];
    }
}

__global__ void scan2_kernel(int* partials, int nb) {
    int t = threadIdx.x;
    int own = (t < nb) ? partials[t] : 0;
    int v = own;
    for (int off = 1; off < 64; off <<= 1) {
        int y = __shfl_up(v, off, 64);
        if (t >= off) v += y;
    }
    if (t < nb) partials[t] = v - own;
}

__global__ void scan3_kernel(int* __restrict__ offs, const int* __restrict__ partials, int n) {
    int base = blockIdx.x * 1024 + threadIdx.x;
    int add = partials[blockIdx.x];
#pragma unroll
    for (int i = 0; i < 4; ++i) {
        int idx = base + i * 256;
        if (idx < n) offs[idx] += add;
    }
}

// 8 lanes per edge, TWO edges per thread. Per edge: hsW8 row (8 B/lane,
// L2-resident 3.2 MB fp8 table) + combb (16 B/lane, L2-hot).
// Leader: sigmoid + CSR slot + rec store.
__global__ void alpha_scatter_kernel(const uint2* __restrict__ epack,
                                     const unsigned char* __restrict__ hsW8,
                                     const unsigned short* __restrict__ combb,
                                     const float* __restrict__ walpha_w,
                                     const float* __restrict__ walpha_b,
                                     int* __restrict__ offs, int2* __restrict__ rec,
                                     int E, int half) {
    int tid = blockIdx.x * blockDim.x + threadIdx.x;
    int e0 = tid >> 3;
    int l = tid & 7;
    if (e0 >= half) return;
    int e1 = e0 + half;
    bool has1 = (e1 < E);

    uint2 p0 = epack[e0];
    uint2 p1 = has1 ? epack[e1] : make_uint2(0u, 0u);
    unsigned sub0 = p0.x & 0x1FFFF, comb0 = p0.x >> 17;
    unsigned sub1 = p1.x & 0x1FFFF, comb1 = p1.x >> 17;
    int obj0 = (int)p0.y, obj1 = (int)p1.y;

    uint2 hv0 = *(const uint2*)(hsW8 + (size_t)sub0 * D64 + l * 8);
    uint4 cv0 = *(const uint4*)(combb + (size_t)comb0 * D64 + l * 8);
    uint2 hv1 = *(const uint2*)(hsW8 + (size_t)sub1 * D64 + l * 8);
    uint4 cv1 = *(const uint4*)(combb + (size_t)comb1 * D64 + l * 8);
    const float4* w = (const float4*)(walpha_w + l * 8);
    float4 w0 = w[0], w1 = w[1];

    float x0, x1;
    x0 = fmaxf(fp8f(hv0.x & 0xFF)         + bf16_lo(cv0.x), 0.f) * w0.x;
    x0 = fmaf(fmaxf(fp8f((hv0.x >> 8) & 0xFF)  + bf16_hi(cv0.x), 0.f), w0.y, x0);
    x0 = fmaf(fmaxf(fp8f((hv0.x >> 16) & 0xFF) + bf16_lo(cv0.y), 0.f), w0.z, x0);
    x0 = fmaf(fmaxf(fp8f(hv0.x >> 24)          + bf16_hi(cv0.y), 0.f), w0.w, x0);
    x0 = fmaf(fmaxf(fp8f(hv0.y & 0xFF)         + bf16_lo(cv0.z), 0.f), w1.x, x0);
    x0 = fmaf(fmaxf(fp8f((hv0.y >> 8) & 0xFF)  + bf16_hi(cv0.z), 0.f), w1.y, x0);
    x0 = fmaf(fmaxf(fp8f((hv0.y >> 16) & 0xFF) + bf16_lo(cv0.w), 0.f), w1.z, x0);
    x0 = fmaf(fmaxf(fp8f(hv0.y >> 24)          + bf16_hi(cv0.w), 0.f), w1.w, x0);

    x1 = fmaxf(fp8f(hv1.x & 0xFF)         + bf16_lo(cv1.x), 0.f) * w0.x;
    x1 = fmaf(fmaxf(fp8f((hv1.x >> 8) & 0xFF)  + bf16_hi(cv1.x), 0.f), w0.y, x1);
    x1 = fmaf(fmaxf(fp8f((hv1.x >> 16) & 0xFF) + bf16_lo(cv1.y), 0.f), w0.z, x1);
    x1 = fmaf(fmaxf(fp8f(hv1.x >> 24)          + bf16_hi(cv1.y), 0.f), w0.w, x1);
    x1 = fmaf(fmaxf(fp8f(hv1.y & 0xFF)         + bf16_lo(cv1.z), 0.f), w1.x, x1);
    x1 = fmaf(fmaxf(fp8f((hv1.y >> 8) & 0xFF)  + bf16_hi(cv1.z), 0.f), w1.y, x1);
    x1 = fmaf(fmaxf(fp8f((hv1.y >> 16) & 0xFF) + bf16_lo(cv1.w), 0.f), w1.z, x1);
    x1 = fmaf(fmaxf(fp8f(hv1.y >> 24)          + bf16_hi(cv1.w), 0.f), w1.w, x1);

    x0 += __shfl_xor(x0, 4, 64);
    x1 += __shfl_xor(x1, 4, 64);
    x0 += __shfl_xor(x0, 2, 64);
    x1 += __shfl_xor(x1, 2, 64);
    x0 += __shfl_xor(x0, 1, 64);
    x1 += __shfl_xor(x1, 1, 64);

    if (l == 0) {
        float wb = walpha_b[0];
        float a0 = 1.f / (1.f + __expf(-(x0 + wb)));
        int rel0 = comb0 >> 5;
        int slot0 = atomicAdd(&offs[obj0], 1);
        rec[slot0] = make_int2((int)(sub0 | (rel0 << 17)), __float_as_int(a0));
        if (has1) {
            float a1 = 1.f / (1.f + __expf(-(x1 + wb)));
            int rel1 = comb1 >> 5;
            int slot1 = atomicAdd(&offs[obj1], 1);
            rec[slot1] = make_int2((int)(sub1 | (rel1 << 17)), __float_as_int(a1));
        }
    }
}

// One wave per node: CSR gather-FMA (8-deep unroll, 16 gathers in flight),
// writes aggb as bf16.
__global__ void agg_kernel(const int2* __restrict__ rec, const int* __restrict__ endoff,
                           const unsigned short* __restrict__ hiddenb,
                           const unsigned short* __restrict__ hrmapb,
                           unsigned short* __restrict__ aggb, int NN) {
    int tid = threadIdx.x;
    int lane = tid & 63;
    int n = (blockIdx.x * blockDim.x + tid) >> 6;
    if (n >= NN) return;
    int start = (n == 0) ? 0 : endoff[n - 1];
    int end = endoff[n];
    start = __builtin_amdgcn_readfirstlane(start);
    end = __builtin_amdgcn_readfirstlane(end);
    float acc0 = 0.f, acc1 = 0.f, acc2 = 0.f, acc3 = 0.f;
    for (int base = start; base < end; base += 64) {
        int cnt = end - base;
        if (cnt > 64) cnt = 64;
        int rx = 0, ry = 0;
        if (lane < cnt) {
            int2 r = rec[base + lane];
            rx = r.x; ry = r.y;
        }
        int j = 0;
        for (; j + 7 < cnt; j += 8) {
            int a_rx[8], a_ry[8];
#pragma unroll
            for (int k = 0; k < 8; ++k) {
                a_rx[k] = __builtin_amdgcn_readlane(rx, j + k);
                a_ry[k] = __builtin_amdgcn_readlane(ry, j + k);
            }
            float h[8], m[8];
#pragma unroll
            for (int k = 0; k < 8; ++k) {
                h[k] = bf16u(hiddenb[(size_t)(a_rx[k] & 0x1FFFF) * D64 + lane]);
                m[k] = bf16u(hrmapb[(size_t)((unsigned)a_rx[k] >> 17) * D64 + lane]);
            }
            acc0 = fmaf(__uint_as_float(a_ry[0]) * h[0], m[0], acc0);
            acc1 = fmaf(__uint_as_float(a_ry[1]) * h[1], m[1], acc1);
            acc2 = fmaf(__uint_as_float(a_ry[2]) * h[2], m[2], acc2);
            acc3 = fmaf(__uint_as_float(a_ry[3]) * h[3], m[3], acc3);
            acc0 = fmaf(__uint_as_float(a_ry[4]) * h[4], m[4], acc0);
            acc1 = fmaf(__uint_as_float(a_ry[5]) * h[5], m[5], acc1);
            acc2 = fmaf(__uint_as_float(a_ry[6]) * h[6], m[6], acc2);
            acc3 = fmaf(__uint_as_float(a_ry[7]) * h[7], m[7], acc3);
        }
        for (; j + 3 < cnt; j += 4) {
            int rx0 = __builtin_amdgcn_readlane(rx, j);
            int ry0 = __builtin_amdgcn_readlane(ry, j);
            int rx1 = __builtin_amdgcn_readlane(rx, j + 1);
            int ry1 = __builtin_amdgcn_readlane(ry, j + 1);
            int rx2 = __builtin_amdgcn_readlane(rx, j + 2);
            int ry2 = __builtin_amdgcn_readlane(ry, j + 2);
            int rx3 = __builtin_amdgcn_readlane(rx, j + 3);
            int ry3 = __builtin_amdgcn_readlane(ry, j + 3);
            float h0 = bf16u(hiddenb[(size_t)(rx0 & 0x1FFFF) * D64 + lane]);
            float m0 = bf16u(hrmapb[(size_t)((unsigned)rx0 >> 17) * D64 + lane]);
            float h1 = bf16u(hiddenb[(size_t)(rx1 & 0x1FFFF) * D64 + lane]);
            float m1 = bf16u(hrmapb[(size_t)((unsigned)rx1 >> 17) * D64 + lane]);
            float h2 = bf16u(hiddenb[(size_t)(rx2 & 0x1FFFF) * D64 + lane]);
            float m2 = bf16u(hrmapb[(size_t)((unsigned)rx2 >> 17) * D64 + lane]);
            float h3 = bf16u(hiddenb[(size_t)(rx3 & 0x1FFFF) * D64 + lane]);
            float m3 = bf16u(hrmapb[(size_t)((unsigned)rx3 >> 17) * D64 + lane]);
            acc0 = fmaf(__uint_as_float(ry0) * h0, m0, acc0);
            acc1 = fmaf(__uint_as_float(ry1) * h1, m1, acc1);
            acc2 = fmaf(__uint_as_float(ry2) * h2, m2, acc2);
            acc3 = fmaf(__uint_as_float(ry3) * h3, m3, acc3);
        }
        for (; j < cnt; ++j) {
            int rx0 = __builtin_amdgcn_readlane(rx, j);
            int ry0 = __builtin_amdgcn_readlane(ry, j);
            float h0 = bf16u(hiddenb[(size_t)(rx0 & 0x1FFFF) * D64 + lane]);
            float m0 = bf16u(hrmapb[(size_t)((unsigned)rx0 >> 17) * D64 + lane]);
            acc0 = fmaf(__uint_as_float(ry0) * h0, m0, acc0);
        }
    }
    aggb[(size_t)n * D64 + lane] = f2bf((acc0 + acc1) + (acc2 + acc3));
}

// out = relu(aggb @ Wh.T) via MFMA; A-fragments direct from global.
__global__ void rowmm_wh_kernel(const unsigned short* __restrict__ aggb,
                                const unsigned short* __restrict__ WhB,
                                float* __restrict__ out, int nrows) {
    int lane = threadIdx.x;
    int rbase = blockIdx.x * 16;
    if (rbase >= nrows) return;

    short8 bfrag[8];
#pragma unroll
    for (int t = 0; t < 4; ++t)
#pragma unroll
        for (int kk = 0; kk < 2; ++kk)
            bfrag[t * 2 + kk] = *(const short8*)(WhB + (size_t)(t * 16 + (lane & 15)) * D64 +
                                                 kk * 32 + (lane >> 4) * 8);

    f32x4 acc[4];
#pragma unroll
    for (int t = 0; t < 4; ++t) acc[t] = (f32x4){0.f, 0.f, 0.f, 0.f};
#pragma unroll
    for (int kk = 0; kk < 2; ++kk) {
        short8 afrag = *(const short8*)(aggb + (size_t)(rbase + (lane & 15)) * D64 +
                                        kk * 32 + (lane >> 4) * 8);
#pragma unroll
        for (int t = 0; t < 4; ++t)
            acc[t] = __builtin_amdgcn_mfma_f32_16x16x32_bf16(afrag, bfrag[t * 2 + kk],
                                                             acc[t], 0, 0, 0);
    }
#pragma unroll
    for (int t = 0; t < 4; ++t)
#pragma unroll
        for (int reg = 0; reg < 4; ++reg) {
            int row = rbase + (lane >> 4) * 4 + reg;
            int col = t * 16 + (lane & 15);
            if (row < nrows)
                out[(size_t)row * D64 + col] = fmaxf(acc[t][reg], 0.f);
        }
}

extern "C" void kernel_launch(void* const* d_in, const int* in_sizes, int n_in,
                              void* d_out, int out_size, void* d_ws, size_t ws_size,
                              hipStream_t stream) {
    const float* hidden   = (const float*)d_in[0];
    const int*   edges    = (const int*)d_in[1];
    const float* emb_rel  = (const float*)d_in[2];
    const int*   mapping  = (const int*)d_in[3];
    const int*   q_rel    = (const int*)d_in[4];
    const int*   r_idx    = (const int*)d_in[5];
    const float* Ws_w     = (const float*)d_in[7];
    const float* Wr_w     = (const float*)d_in[8];
    const float* Wqr_w    = (const float*)d_in[9];
    const float* Wqr_b    = (const float*)d_in[10];
    const float* walpha_w = (const float*)d_in[11];
    const float* walpha_b = (const float*)d_in[12];
    const float* Wh_w     = (const float*)d_in[13];
    float* out = (float*)d_out;

    int NN   = in_sizes[0] / D64;   // 50000
    int E    = in_sizes[5];         // 800000
    int NREL = in_sizes[3];         // 475
    int NQ   = in_sizes[4];         // 32

    // workspace layout (~25 MB); aggb aliases epack (dead after alpha_scatter)
    char* ws = (char*)d_ws;
    size_t off = 0;
    unsigned char*  hsW8    = (unsigned char*)(ws + off); off += (size_t)NN * D64;       // 3.2 MB
    unsigned short* hiddenb = (unsigned short*)(ws + off); off += (size_t)NN * D64 * 2;  // 6.4 MB
    int2*  rec  = (int2*)(ws + off);       off += (size_t)E * sizeof(int2);              // 6.4 MB
    uint2* epack = (uint2*)(ws + off);     off += (size_t)E * sizeof(uint2);             // 6.4 MB
    unsigned short* aggb = (unsigned short*)epack;  // alias: epack dead before agg runs
    int* counts = (int*)(ws + off);        off += (size_t)NN * sizeof(int);              // 0.2 MB
    int* offs   = (int*)(ws + off);        off += (size_t)NN * sizeof(int);              // 0.2 MB
    int* partials = (int*)(ws + off);      off += 64 * sizeof(int);
    unsigned short* hrmapb = (unsigned short*)(ws + off); off += (size_t)NREL * D64 * 2;
    unsigned short* hrWb   = (unsigned short*)(ws + off); off += (size_t)NREL * D64 * 2;
    unsigned short* qrb    = (unsigned short*)(ws + off); off += (size_t)NQ * D64 * 2;
    unsigned short* WsB    = (unsigned short*)(ws + off); off += (size_t)D64 * D64 * 2;  // 8 KB
    unsigned short* WhB    = (unsigned short*)(ws + off); off += (size_t)D64 * D64 * 2;  // 8 KB
    unsigned short* combb  = (unsigned short*)(ws + off); off += (size_t)NREL * 32 * D64 * 2; // 1.9 MB

    int NB = (NN + 1023) / 1024;  // scan blocks (49)
    int zblocks = (NN + 63) / 64;

    prep_kernel<<<NREL + NQ + 128 + zblocks, 64, 0, stream>>>(
        emb_rel, mapping, q_rel, Wr_w, Wqr_w, Wqr_b, Ws_w, Wh_w,
        hrmapb, hrWb, qrb, WsB, WhB, counts, NREL, NQ, NN);
    comb_kernel<<<(NREL * 32 * D64 + 255) / 256, 256, 0, stream>>>(hrWb, qrb, combb, NREL);
    rowmm_mfma_kernel<<<(NN + 15) / 16, 64, 0, stream>>>(hidden, WsB, hsW8, hiddenb, NN,
                                                         edges, r_idx, counts, epack, E);
    scan1_kernel<<<NB, 256, 0, stream>>>(counts, offs, partials, NN);
    scan2_kernel<<<1, 64, 0, stream>>>(partials, NB);
    scan3_kernel<<<NB, 256, 0, stream>>>(offs, partials, NN);
    {
        int half = (E + 1) / 2;
        long long threads = (long long)half * 8;
        int blocks = (int)((threads + 255) / 256);
        alpha_scatter_kernel<<<blocks, 256, 0, stream>>>(epack, hsW8, combb,
                                                         walpha_w, walpha_b, offs, rec, E, half);
    }
    agg_kernel<<<(NN * 64 + 1023) / 1024, 1024, 0, stream>>>(rec, offs, hiddenb, hrmapb,
                                                             aggb, NN);
    rowmm_wh_kernel<<<(NN + 15) / 16, 64, 0, stream>>>(aggb, WhB, out, NN);
}